// Round 7
// baseline (3559.039 us; speedup 1.0000x reference)
//
#include <hip/hip_runtime.h>
#include <stdint.h>
#include <math.h>

#define NB 8
#define NDIM 384
#define NHD 8
#define DHD 48

// ---------------- persistent device buffers (f32) ----------------
__device__ float g_patch[2048 * 1536];
__device__ float g_x[NB * 256 * NDIM];
__device__ float g_xb[NB * 64 * NDIM];
__device__ float g_xq[NB * NHD * 256 * DHD];
__device__ float g_xk[NB * NHD * 256 * DHD];
__device__ float g_xv[NB * NHD * 256 * DHD];
__device__ float g_q4[NB * 256 * NDIM];
__device__ float g_k4[NB * 256 * NDIM];
__device__ float g_q[NB * 256 * NDIM];
__device__ float g_k[NB * 256 * NDIM];
__device__ float g_rm0[NB * 256 * NHD];
__device__ float g_rm[NB * 64];
__device__ float g_rmd[NB * NHD * 256];
__device__ float g_logits[NB * 256 * 64];
__device__ float g_tmp[NB * 64 * 256];
__device__ float g_e1[NB * 64 * 256];
__device__ float g_adj2[NB * 64 * 64];
__device__ float g_lg2[NB * 64];

__device__ __forceinline__ float* dev_buf(int s) {
  switch (s) {
    case 0: return g_patch;
    case 1: return g_x;
    case 2: return g_q4;
    case 3: return g_k4;
    case 4: return g_q;
    case 5: return g_k;
    case 6: return g_logits;
    default: return nullptr;
  }
}
#define SEL_PATCH 0
#define SEL_X 1
#define SEL_Q4 2
#define SEL_K4 3
#define SEL_Q 4
#define SEL_K 5
#define SEL_LOGITS 6

__device__ __forceinline__ float gelu_f(float x) {
  return 0.5f * x * (1.0f + erff(x * 0.70710678118654752440f));
}

// ---------------- JAX threefry2x32 (20 rounds) ----------------
__host__ __device__ inline void threefry2x32(uint32_t k0, uint32_t k1,
                                             uint32_t x0, uint32_t x1,
                                             uint32_t* o0, uint32_t* o1) {
  uint32_t ks2 = k0 ^ k1 ^ 0x1BD11BDAu;
#define TF_R(r) { x0 += x1; x1 = (x1 << (r)) | (x1 >> (32 - (r))); x1 ^= x0; }
  x0 += k0; x1 += k1;
  TF_R(13) TF_R(15) TF_R(26) TF_R(6)
  x0 += k1; x1 += ks2 + 1u;
  TF_R(17) TF_R(29) TF_R(16) TF_R(24)
  x0 += ks2; x1 += k0 + 2u;
  TF_R(13) TF_R(15) TF_R(26) TF_R(6)
  x0 += k0; x1 += k1 + 3u;
  TF_R(17) TF_R(29) TF_R(16) TF_R(24)
  x0 += k1; x1 += ks2 + 4u;
  TF_R(13) TF_R(15) TF_R(26) TF_R(6)
  x0 += ks2; x1 += k0 + 5u;
#undef TF_R
  *o0 = x0; *o1 = x1;
}

// modern JAX threefry_partitionable: counter (0, idx), bits = o0 ^ o1
__device__ __forceinline__ double gumbel_from(uint32_t k0, uint32_t k1,
                                              uint32_t idx) {
  uint32_t o0, o1;
  threefry2x32(k0, k1, 0u, idx, &o0, &o1);
  uint32_t bits = o0 ^ o1;
  uint32_t ub = (bits >> 9) | 0x3f800000u;
  float f = __uint_as_float(ub) - 1.0f;
  const float tiny = 1.17549435e-38f;
  float u = fmaxf(f + tiny, tiny);
  return -log(-log((double)u));
}

// ---------------- patch pipeline: conv1+BN+GELU+dwconv2+maxpool ----------------
__global__ __launch_bounds__(256) void k_patch(const float* __restrict__ img,
                                               const float* __restrict__ w1, const float* __restrict__ b1,
                                               const float* __restrict__ bng, const float* __restrict__ bnb,
                                               const float* __restrict__ w2, const float* __restrict__ b2) {
  __shared__ float s_in[3 * 16 * 16];
  __shared__ float s_c1[192 * 49];
  const float BN_INV = (float)0.99999500003749968752;
  int p = blockIdx.x;
  int b = p >> 8, g = p & 255, gi = g >> 4, gj = g & 15;
  int tid = threadIdx.x;
  for (int i = tid; i < 3 * 256; i += 256) s_in[i] = 0.f;
  __syncthreads();
  for (int idx = tid; idx < 3 * 196; idx += 256) {
    int c = idx / 196, r = idx % 196, py = r / 14, px = r % 14;
    s_in[c * 256 + (py + 1) * 16 + (px + 1)] =
        img[(((size_t)b * 3 + c) * 224 + gi * 14 + py) * 224 + gj * 14 + px];
  }
  __syncthreads();
  int wave = tid >> 6, lane = tid & 63;
  int y = lane / 7, x = lane - y * 7;
  bool act = lane < 49;
  float in[27];
#pragma unroll
  for (int c = 0; c < 3; ++c)
#pragma unroll
    for (int ky = 0; ky < 3; ++ky)
#pragma unroll
      for (int kx = 0; kx < 3; ++kx)
        in[c * 9 + ky * 3 + kx] = act ? s_in[c * 256 + (2 * y + ky) * 16 + (2 * x + kx)] : 0.f;

  for (int chunk = 0; chunk < 2; ++chunk) {
    int obase = chunk * 192;
    for (int ci = 0; ci < 48; ci += 2) {
      int cl0 = wave * 48 + ci;
      int o0 = obase + cl0, o1 = o0 + 1;
      float a0 = b1[o0], a1 = b1[o1];
      const float* wA = w1 + o0 * 27;
      const float* wB = w1 + o1 * 27;
#pragma unroll
      for (int j = 0; j < 27; ++j) {
        a0 += in[j] * wA[j];
        a1 += in[j] * wB[j];
      }
      a0 = a0 * BN_INV * bng[o0] + bnb[o0];
      a1 = a1 * BN_INV * bng[o1] + bnb[o1];
      if (act) {
        s_c1[cl0 * 49 + lane] = gelu_f(a0);
        s_c1[(cl0 + 1) * 49 + lane] = gelu_f(a1);
      }
    }
    __syncthreads();
    if (tid < 192) {
      int cl = tid, c = obase + cl;
      float wd[9];
#pragma unroll
      for (int j = 0; j < 9; ++j) wd[j] = w2[c * 9 + j];
      float bb2 = b2[c];
      const float* sc = &s_c1[cl * 49];
      float o2[4][4];
#pragma unroll
      for (int yy = 0; yy < 4; ++yy)
#pragma unroll
        for (int xx = 0; xx < 4; ++xx) {
          float a = bb2;
#pragma unroll
          for (int ky = 0; ky < 3; ++ky) {
            int iy = 2 * yy + ky - 1;
            if (iy < 0 || iy >= 7) continue;
#pragma unroll
            for (int kx = 0; kx < 3; ++kx) {
              int ix = 2 * xx + kx - 1;
              if (ix < 0 || ix >= 7) continue;
              a += sc[iy * 7 + ix] * wd[ky * 3 + kx];
            }
          }
          o2[yy][xx] = a;
        }
      float4 r;
      r.x = fmaxf(fmaxf(o2[0][0], o2[0][1]), fmaxf(o2[1][0], o2[1][1]));
      r.y = fmaxf(fmaxf(o2[0][2], o2[0][3]), fmaxf(o2[1][2], o2[1][3]));
      r.z = fmaxf(fmaxf(o2[2][0], o2[2][1]), fmaxf(o2[3][0], o2[3][1]));
      r.w = fmaxf(fmaxf(o2[2][2], o2[2][3]), fmaxf(o2[3][2], o2[3][3]));
      *(float4*)&g_patch[(size_t)p * 1536 + c * 4] = r;
    }
    __syncthreads();
  }
}

// ---------------- generic GEMM (K mult of 384): C = act(A@W + bias) (+resid) ----------------
// pipelined W-quad prefetch; threads = N
template <int RPB>
__global__ void k_gemm(const float* __restrict__ W, const float* __restrict__ bias,
                       int selA, int selC, int selR,
                       int M, int K, int N, int act) {
  extern __shared__ float sA[];   // RPB * 384
  const float* A = dev_buf(selA);
  float* C = dev_buf(selC);
  const float* R = (selR >= 0) ? dev_buf(selR) : nullptr;
  int tid = threadIdx.x;
  int bs = blockDim.x;
  int r0 = blockIdx.x * RPB;
  float acc[RPB];
#pragma unroll
  for (int r = 0; r < RPB; ++r) acc[r] = 0.0f;
  const float4 z4 = {0.f, 0.f, 0.f, 0.f};
  for (int k0 = 0; k0 < K; k0 += 384) {
    __syncthreads();
    for (int idx = tid; idx < RPB * 96; idx += bs) {
      int r = idx / 96, q = idx - r * 96;
      int m = r0 + r;
      ((float4*)sA)[idx] = (m < M) ? ((const float4*)(A + (size_t)m * K + k0))[q] : z4;
    }
    __syncthreads();
    const float* Wp = W + (size_t)k0 * N + tid;
    float w0 = Wp[0], w1 = Wp[N], w2 = Wp[2 * (size_t)N], w3 = Wp[3 * (size_t)N];
#pragma unroll 2
    for (int k = 0; k < 384; k += 4) {
      float n0 = 0.f, n1 = 0.f, n2 = 0.f, n3 = 0.f;
      if (k + 4 < 384) {
        const float* Wn = Wp + (size_t)(k + 4) * N;
        n0 = Wn[0]; n1 = Wn[N]; n2 = Wn[2 * (size_t)N]; n3 = Wn[3 * (size_t)N];
      }
#pragma unroll
      for (int r = 0; r < RPB; ++r) {
        float4 a = *(const float4*)&sA[r * 384 + k];
        acc[r] += a.x * w0 + a.y * w1 + a.z * w2 + a.w * w3;
      }
      w0 = n0; w1 = n1; w2 = n2; w3 = n3;
    }
  }
#pragma unroll
  for (int r = 0; r < RPB; ++r) {
    int m = r0 + r;
    if (m >= M) break;
    float v = acc[r];
    if (bias) v += bias[tid];
    if (act == 1) v = gelu_f(v);
    if (R) v += R[(size_t)m * N + tid];
    C[(size_t)m * N + tid] = v;
  }
}

// ---------------- fused LayerNorm + GCN weight projection ----------------
// block per row (b,tt); threads = 384; writes g_xq/g_xk/g_xv
__global__ __launch_bounds__(384) void k_lngcn(const float* __restrict__ gg, const float* __restrict__ bb,
                                               const float* __restrict__ Wq, const float* __restrict__ Wk,
                                               const float* __restrict__ Wv, int t) {
  __shared__ float xn[NDIM];
  __shared__ float red[128];
  int row = blockIdx.x;          // b*t + tt
  int b = row / t, tt = row - b * t;
  int tid = threadIdx.x;
  float v = g_x[(size_t)row * NDIM + tid];
  // sum reduce
  if (tid < 128) red[tid] = 0.f;
  __syncthreads();
  atomicAdd(&red[tid & 127], v);   // 3 adds per slot
  __syncthreads();
  if (tid < 64) red[tid] += red[tid + 64];
  __syncthreads();
  float mean;
  {
    if (tid < 32) red[tid] += red[tid + 32];
    __syncthreads();
    if (tid < 16) red[tid] += red[tid + 16];
    __syncthreads();
    if (tid < 8) red[tid] += red[tid + 8];
    __syncthreads();
    if (tid < 4) red[tid] += red[tid + 4];
    __syncthreads();
    if (tid < 2) red[tid] += red[tid + 2];
    __syncthreads();
    if (tid < 1) red[tid] += red[tid + 1];
    __syncthreads();
    mean = red[0] * (1.0f / 384.0f);
  }
  __syncthreads();
  float d = v - mean;
  if (tid < 128) red[tid] = 0.f;
  __syncthreads();
  atomicAdd(&red[tid & 127], d * d);
  __syncthreads();
  if (tid < 64) red[tid] += red[tid + 64];
  __syncthreads();
  if (tid < 32) red[tid] += red[tid + 32];
  __syncthreads();
  if (tid < 16) red[tid] += red[tid + 16];
  __syncthreads();
  if (tid < 8) red[tid] += red[tid + 8];
  __syncthreads();
  if (tid < 4) red[tid] += red[tid + 4];
  __syncthreads();
  if (tid < 2) red[tid] += red[tid + 2];
  __syncthreads();
  if (tid < 1) red[tid] += red[tid + 1];
  __syncthreads();
  float var = red[0] * (1.0f / 384.0f);
  float inv = 1.0f / sqrtf(var + 1e-5f);
  xn[tid] = d * inv * gg[tid] + bb[tid];
  __syncthreads();
  // projection: thread -> (h, d)
  int h = tid / DHD, dd = tid - h * DHD;
  const float* xh = &xn[h * DHD];
  float aq = 0.f, ak = 0.f, av = 0.f;
#pragma unroll 4
  for (int e = 0; e < DHD; ++e) {
    float xv_ = xh[e];
    aq += xv_ * Wq[e * DHD + dd];
    ak += xv_ * Wk[e * DHD + dd];
    av += xv_ * Wv[e * DHD + dd];
  }
  size_t o = ((size_t)(b * NHD + h) * t + tt) * DHD + dd;
  g_xq[o] = aq; g_xk[o] = ak; g_xv[o] = av;
}

// ---------------- q4r/k4r = adj @ xq / adj @ xk, stored (b,t,384) ----------------
__global__ __launch_bounds__(64) void k_adjmm(const int* __restrict__ adji, int use_adj2, int t) {
  __shared__ float arow[256];
  int bid = blockIdx.x;
  int l = bid % t; int h = (bid / t) % NHD; int b = bid / (t * NHD);
  int tid = threadIdx.x;
  for (int s = tid; s < t; s += 64)
    arow[s] = use_adj2 ? g_adj2[((size_t)b * t + l) * t + s] : (float)adji[l * 256 + s];
  __syncthreads();
  if (tid < DHD) {
    const float* xq = g_xq + (size_t)((b * NHD + h) * t) * DHD + tid;
    const float* xk = g_xk + (size_t)((b * NHD + h) * t) * DHD + tid;
    float accq = 0.f, acck = 0.f;
#pragma unroll 4
    for (int s = 0; s < t; ++s) {
      float a = arow[s];
      accq += a * xq[(size_t)s * DHD];
      acck += a * xk[(size_t)s * DHD];
    }
    size_t o = ((size_t)b * t + l) * NDIM + h * DHD + tid;
    g_q4[o] = accq; g_k4[o] = acck;
  }
}

// ---------------- rm0 = gelu([q,k] @ w_kf)  (b*t, 8) ----------------
__global__ __launch_bounds__(64) void k_kf(const float* __restrict__ Wkf) {
  int row = blockIdx.x;
  int tid = threadIdx.x;
  const float* qrow = g_q + (size_t)row * NDIM;
  const float* krow = g_k + (size_t)row * NDIM;
  float accs[8];
#pragma unroll
  for (int j = 0; j < 8; ++j) accs[j] = 0.f;
  for (int m = tid; m < 768; m += 64) {
    float v = (m < 384) ? qrow[m] : krow[m - 384];
    const float* wr = Wkf + (size_t)m * 8;
#pragma unroll
    for (int j = 0; j < 8; ++j) accs[j] += v * wr[j];
  }
#pragma unroll
  for (int j = 0; j < 8; ++j) {
    float a = accs[j];
    for (int off = 32; off > 0; off >>= 1) a += __shfl_xor(a, off);
    if (tid == 0) g_rm0[(size_t)row * 8 + j] = gelu_f(a);
  }
}

// ---------------- rm[b,h,g] = sum_t rm0[b,t,h]*rm0[b,t,g] ----------------
__global__ __launch_bounds__(64) void k_rm(int t) {
  int b = blockIdx.x; int tid = threadIdx.x;
  int h = tid >> 3, g = tid & 7;
  const float* base = g_rm0 + (size_t)b * t * 8;
  float acc = 0.f;
  for (int tt = 0; tt < t; ++tt) acc += base[tt * 8 + h] * base[tt * 8 + g];
  g_rm[b * 64 + tid] = acc;
}

// ---------------- rmd = sigmoid((rm @ wkf2)/sD) ----------------
__global__ void k_rmd(const float* __restrict__ Wp, const float* __restrict__ sDp, int t) {
  int id = blockIdx.x * blockDim.x + threadIdx.x;
  int total = NB * NHD * t;
  if (id >= total) return;
  int s = id % t; int h = (id / t) % NHD; int b = id / (t * NHD);
  const float* rm = g_rm + b * 64 + h * 8;
  float acc = 0.f;
#pragma unroll
  for (int g = 0; g < 8; ++g) acc += rm[g] * Wp[g * t + s];
  float val = acc / sDp[h * t + s];
  g_rmd[(size_t)(b * NHD + h) * t + s] = 1.0f / (1.0f + expf(-val));
}

// ---------------- fused attention core: QK dots + gate + mix + masked softmax + attnV ----
// block per (b,l), threads = t. Output v4r row -> g_q4[(b*t+l)*384 + :]
__global__ void k_attn(const float* __restrict__ RM, const int* __restrict__ adji,
                       int use_adj2, int t, float scale) {
  extern __shared__ float lds[];
  float* qs = lds;                 // 384
  float* rmat = qs + NDIM;         // 64
  float* rl = rmat + 64;           // 8
  float* p = rl + 8;               // 8*t
  float* res = p + 8 * t;          // 16
  int bid = blockIdx.x;
  int l = bid % t, b = bid / t;
  int tt = threadIdx.x;
  for (int i = tt; i < NDIM; i += t) qs[i] = g_q[((size_t)b * t + l) * NDIM + i];
  if (tt < 64) rmat[tt] = RM[tt];
  if (tt < 8) rl[tt] = g_rmd[((size_t)(b * NHD + tt)) * t + l];
  __syncthreads();
  // per-thread: 8 head dots with K row tt
  const float* krow = g_k + ((size_t)b * t + tt) * NDIM;
  float s[8];
#pragma unroll
  for (int h = 0; h < 8; ++h) {
    float acc = 0.f;
#pragma unroll
    for (int j = 0; j < 12; ++j) {
      float4 kk = *(const float4*)&krow[h * DHD + j * 4];
      float4 qq = *(const float4*)&qs[h * DHD + j * 4];
      acc += kk.x * qq.x + kk.y * qq.y + kk.z * qq.z + kk.w * qq.w;
    }
    float v = acc * scale;
    v = (v >= 0.f) ? v : 0.01f * v;
    s[h] = rl[h] * v * g_rmd[((size_t)(b * NHD + h)) * t + tt];
  }
  bool m = use_adj2 ? (g_adj2[((size_t)b * t + l) * t + tt] > 0.f)
                    : (adji[l * 256 + tt] > 0);
  float sv[8];
#pragma unroll
  for (int g = 0; g < 8; ++g) {
    float a = 0.f;
#pragma unroll
    for (int h = 0; h < 8; ++h) a += rmat[g * 8 + h] * s[h];
    sv[g] = m ? a : -1e12f;
    p[g * t + tt] = sv[g];
  }
  __syncthreads();
  int GP = t >> 3;                  // lanes per head group (32 or 8)
  int g = tt / GP, j = tt - g * GP;
  // max-reduce per head
  float mval = -1e30f;
  for (int i = j; i < t; i += GP) mval = fmaxf(mval, p[g * t + i]);
  for (int off = GP >> 1; off > 0; off >>= 1) mval = fmaxf(mval, __shfl_xor(mval, off, GP));
  if (j == 0) res[g] = mval;
  __syncthreads();
  // exp
#pragma unroll
  for (int g2 = 0; g2 < 8; ++g2) p[g2 * t + tt] = expf(sv[g2] - res[g2]);
  __syncthreads();
  // sum-reduce per head
  float sval = 0.f;
  for (int i = j; i < t; i += GP) sval += p[g * t + i];
  for (int off = GP >> 1; off > 0; off >>= 1) sval += __shfl_xor(sval, off, GP);
  if (j == 0) res[8 + g] = sval;
  __syncthreads();
  // attnV: outputs o in [0,384)
  for (int o = tt; o < NDIM; o += t) {
    int gg = o / DHD, dd = o - gg * DHD;
    const float* xv = g_xv + ((size_t)(b * NHD + gg) * t) * DHD + dd;
    const float* pa = &p[gg * t];
    float acc = 0.f;
#pragma unroll 4
    for (int s2 = 0; s2 < t; ++s2) acc += pa[s2] * xv[(size_t)s2 * DHD];
    g_q4[((size_t)b * t + l) * NDIM + o] = acc / res[8 + gg];
  }
}

// ---------------- gumbel softmax for pooling: tmp[b,j,:] over 256 ----------------
__global__ __launch_bounds__(256) void k_gumbel_pool(uint32_t k0, uint32_t k1) {
  __shared__ double red2[256];
  int bj = blockIdx.x;   // b*64 + j
  int b = bj >> 6, j = bj & 63;
  int tt = threadIdx.x;
  uint32_t n = (uint32_t)bj * 256u + (uint32_t)tt;
  double gum = gumbel_from(k0, k1, n);
  double val = (double)g_logits[((size_t)b * 256 + tt) * 64 + j] + gum;
  red2[tt] = val; __syncthreads();
  for (int s = 128; s > 0; s >>= 1) { if (tt < s) red2[tt] = fmax(red2[tt], red2[tt + s]); __syncthreads(); }
  double mx = red2[0]; __syncthreads();
  double e = exp(val - mx);
  red2[tt] = e; __syncthreads();
  for (int s = 128; s > 0; s >>= 1) { if (tt < s) red2[tt] += red2[tt + s]; __syncthreads(); }
  g_tmp[(size_t)bj * 256 + tt] = (float)(e / red2[0]);
}

// ---------------- xb[b,j,:] = tmp[b,j,:] @ x[b,:,:] ----------------
__global__ __launch_bounds__(384) void k_poolx() {
  __shared__ float trow[256];
  int bj = blockIdx.x; int b = bj >> 6;
  int tid = threadIdx.x;
  if (tid < 256) trow[tid] = g_tmp[(size_t)bj * 256 + tid];
  __syncthreads();
  float acc = 0.f;
  const float* xb = g_x + (size_t)b * 256 * NDIM + tid;
  for (int tt = 0; tt < 256; ++tt) acc += trow[tt] * xb[(size_t)tt * NDIM];
  g_xb[(size_t)bj * NDIM + tid] = acc;
}

__global__ void k_copyx(int n) {
  int i = blockIdx.x * blockDim.x + threadIdx.x;
  if (i < n) g_x[i] = g_xb[i];
}

// ---------------- e1[b,l,t] = sum_s tmp[b,l,s]*adj[s,t] ----------------
__global__ __launch_bounds__(256) void k_pooladj1(const int* __restrict__ adji) {
  __shared__ float trow[256];
  int bl = blockIdx.x;
  int tid = threadIdx.x;
  trow[tid] = g_tmp[(size_t)bl * 256 + tid];
  __syncthreads();
  float acc = 0.f;
  for (int s = 0; s < 256; ++s) acc += trow[s] * (float)adji[s * 256 + tid];
  g_e1[(size_t)bl * 256 + tid] = acc;
}

// ---------------- adj2[b,l,m] = sum_t e1[b,l,t]*tmp[b,m,t] ----------------
__global__ __launch_bounds__(64) void k_pooladj2() {
  __shared__ float erow[256];
  int bl = blockIdx.x; int b = bl >> 6;
  int tid = threadIdx.x;
  for (int s = tid; s < 256; s += 64) erow[s] = g_e1[(size_t)bl * 256 + s];
  __syncthreads();
  const float* tm = g_tmp + ((size_t)b * 64 + tid) * 256;
  float acc = 0.f;
  for (int s = 0; s < 256; ++s) acc += erow[s] * tm[s];
  g_adj2[(size_t)bl * 64 + tid] = acc;
}

// ---------------- final logits: x @ upoolout_w + b ----------------
__global__ __launch_bounds__(64) void k_outlogits(const float* __restrict__ w, const float* __restrict__ bias) {
  int row = blockIdx.x;
  int tid = threadIdx.x;
  const float* x = g_x + (size_t)row * NDIM;
  float acc = 0.f;
  for (int c = tid; c < NDIM; c += 64) acc += x[c] * w[c];
  for (int off = 32; off > 0; off >>= 1) acc += __shfl_xor(acc, off);
  if (tid == 0) g_lg2[row] = acc + bias[0];
}

// ---------------- final gumbel softmax + weighted sum -> out ----------------
__global__ __launch_bounds__(384) void k_final(uint32_t k0, uint32_t k1, float* __restrict__ out) {
  __shared__ double sv[64];
  __shared__ double sp[64];
  int b = blockIdx.x;
  int tid = threadIdx.x;
  if (tid < 64) {
    uint32_t n = (uint32_t)(b * 64 + tid);
    sv[tid] = (double)g_lg2[b * 64 + tid] + gumbel_from(k0, k1, n);
  }
  __syncthreads();
  double mx = -1e30;
  for (int i2 = 0; i2 < 64; ++i2) mx = fmax(mx, sv[i2]);
  if (tid < 64) sp[tid] = exp(sv[tid] - mx);
  __syncthreads();
  double sum = 0.;
  for (int i2 = 0; i2 < 64; ++i2) sum += sp[i2];
  float acc = 0.f;
  const float* xb = g_x + (size_t)b * 64 * NDIM + tid;
  for (int tt = 0; tt < 64; ++tt) acc += (float)(sp[tt] / sum) * xb[(size_t)tt * NDIM];
  out[(size_t)b * NDIM + tid] = acc;
}

// ---------------- host ----------------
extern "C" void kernel_launch(void* const* d_in, const int* in_sizes, int n_in,
                              void* d_out, int out_size, void* d_ws, size_t ws_size,
                              hipStream_t stream) {
  const float* img = (const float*)d_in[0];
  const int* adj = (const int*)d_in[1];
  const float* ln_g = (const float*)d_in[2];
  const float* ln_b = (const float*)d_in[3];
  const float* gcn_wq = (const float*)d_in[4];
  const float* gcn_wk = (const float*)d_in[5];
  const float* gcn_wv = (const float*)d_in[6];
  const float* wq = (const float*)d_in[7];
  const float* wk = (const float*)d_in[8];
  const float* wv = (const float*)d_in[9];
  const float* w_kf = (const float*)d_in[10];
  const float* w_kf2 = (const float*)d_in[11];
  const float* w_kf3 = (const float*)d_in[12];
  const float* sD = (const float*)d_in[13];
  const float* sD2 = (const float*)d_in[14];
  const float* randmat = (const float*)d_in[15];
  const float* conv1_w = (const float*)d_in[16];
  const float* conv1_b = (const float*)d_in[17];
  const float* bn_g = (const float*)d_in[18];
  const float* bn_b = (const float*)d_in[19];
  const float* conv2_w = (const float*)d_in[20];
  const float* conv2_b = (const float*)d_in[21];
  const float* emb_w = (const float*)d_in[22];
  const float* emb_b = (const float*)d_in[23];
  const float* upool_w = (const float*)d_in[24];
  const float* upool_b = (const float*)d_in[25];
  const float* upoolout_w = (const float*)d_in[26];
  const float* upoolout_b = (const float*)d_in[27];
  float* out = (float*)d_out;

  uint32_t k2a, k2b, k99a, k99b;
  threefry2x32(0u, 42u, 0u, 2u, &k2a, &k2b);
  threefry2x32(0u, 42u, 0u, 99u, &k99a, &k99b);

  const float SCALE = (float)(1.0 / sqrt(384.0));

  k_patch<<<2048, 256, 0, stream>>>(img, conv1_w, conv1_b, bn_g, bn_b, conv2_w, conv2_b);
  k_gemm<4><<<512, 384, 4 * 384 * sizeof(float), stream>>>(
      emb_w, emb_b, SEL_PATCH, SEL_X, -1, 2048, 1536, 384, 0);

  auto attention = [&](int i, int t, int label) {
    int rows = NB * t;
    int bht = NB * NHD * t;
    int use_adj2 = (t == 64) ? 1 : 0;
    k_lngcn<<<rows, 384, 0, stream>>>(ln_g + i * 384, ln_b + i * 384,
                                      gcn_wq + i * 2304, gcn_wk + i * 2304,
                                      gcn_wv + i * 2304, t);
    k_adjmm<<<bht, 64, 0, stream>>>(adj, use_adj2, t);
    if (rows == 2048) {
      k_gemm<4><<<512, 384, 4 * 384 * sizeof(float), stream>>>(
          wq + i * 147456, nullptr, SEL_Q4, SEL_Q, -1, rows, 384, 384, 0);
      k_gemm<4><<<512, 384, 4 * 384 * sizeof(float), stream>>>(
          wk + i * 147456, nullptr, SEL_K4, SEL_K, -1, rows, 384, 384, 0);
    } else {
      k_gemm<2><<<256, 384, 2 * 384 * sizeof(float), stream>>>(
          wq + i * 147456, nullptr, SEL_Q4, SEL_Q, -1, rows, 384, 384, 0);
      k_gemm<2><<<256, 384, 2 * 384 * sizeof(float), stream>>>(
          wk + i * 147456, nullptr, SEL_K4, SEL_K, -1, rows, 384, 384, 0);
    }
    k_kf<<<rows, 64, 0, stream>>>(w_kf + i * 6144);
    k_rm<<<NB, 64, 0, stream>>>(t);
    const float* Wp = label ? (w_kf3 + i * 512) : (w_kf2 + i * 2048);
    const float* sDp = label ? (sD2 + i * 512) : (sD + i * 2048);
    int totr = NB * NHD * t;
    k_rmd<<<(totr + 255) / 256, 256, 0, stream>>>(Wp, sDp, t);
    size_t attn_lds = (NDIM + 64 + 8 + 8 * t + 16) * sizeof(float);
    k_attn<<<rows, t, attn_lds, stream>>>(randmat + i * 64, adj, use_adj2, t, SCALE);
    if (rows == 2048) {
      k_gemm<4><<<512, 384, 4 * 384 * sizeof(float), stream>>>(
          wv + i * 147456, nullptr, SEL_Q4, SEL_X, SEL_X, rows, 384, 384, 1);
    } else {
      k_gemm<2><<<256, 384, 2 * 384 * sizeof(float), stream>>>(
          wv + i * 147456, nullptr, SEL_Q4, SEL_X, SEL_X, rows, 384, 384, 1);
    }
  };

  attention(0, 256, 0);
  attention(1, 256, 0);

  // pooling at i==2
  k_gemm<2><<<1024, 64, 2 * 384 * sizeof(float), stream>>>(
      upool_w, upool_b, SEL_X, SEL_LOGITS, -1, 2048, 384, 64, 0);
  k_gumbel_pool<<<512, 256, 0, stream>>>(k2a, k2b);
  k_poolx<<<512, 384, 0, stream>>>();
  k_copyx<<<(NB * 64 * NDIM + 255) / 256, 256, 0, stream>>>(NB * 64 * NDIM);
  k_pooladj1<<<512, 256, 0, stream>>>(adj);
  k_pooladj2<<<512, 64, 0, stream>>>();

  attention(2, 64, 1);
  attention(3, 64, 1);

  k_outlogits<<<512, 64, 0, stream>>>(upoolout_w, upoolout_b);
  k_final<<<8, 384, 0, stream>>>(k99a, k99b, out);
}

// Round 8
// 1511.639 us; speedup vs baseline: 2.3544x; 2.3544x over previous
//
#include <hip/hip_runtime.h>
#include <stdint.h>
#include <math.h>

#define NB 8
#define NDIM 384
#define NHD 8
#define DHD 48

// ---------------- persistent device buffers (f32) ----------------
__device__ float g_patch[2048 * 1536];
__device__ float g_x[NB * 256 * NDIM];
__device__ float g_xb[NB * 64 * NDIM];
__device__ float g_xq[NB * NHD * 256 * DHD];
__device__ float g_xk[NB * NHD * 256 * DHD];
__device__ float g_xv[NB * NHD * 256 * DHD];
__device__ float g_q4[NB * 256 * NDIM];
__device__ float g_k4[NB * 256 * NDIM];
__device__ float g_q[NB * 256 * NDIM];
__device__ float g_k[NB * 256 * NDIM];
__device__ float g_rm0[NB * 256 * NHD];
__device__ float g_rm[NB * 64];
__device__ float g_rmd[NB * NHD * 256];
__device__ float g_score[NB * NHD * 256 * 256];
__device__ float g_score2[NB * NHD * 256 * 256];
__device__ float g_logits[NB * 256 * 64];
__device__ float g_tmp[NB * 64 * 256];
__device__ float g_e1[NB * 64 * 256];
__device__ float g_adj2[NB * 64 * 64];
__device__ float g_lg2[NB * 64];

__device__ __forceinline__ float* dev_buf(int s) {
  switch (s) {
    case 0: return g_patch;
    case 1: return g_x;
    case 2: return g_q4;
    case 3: return g_k4;
    case 4: return g_q;
    case 5: return g_k;
    case 6: return g_logits;
    default: return nullptr;
  }
}
#define SEL_PATCH 0
#define SEL_X 1
#define SEL_Q4 2
#define SEL_K4 3
#define SEL_Q 4
#define SEL_K 5
#define SEL_LOGITS 6

__device__ __forceinline__ float gelu_f(float x) {
  return 0.5f * x * (1.0f + erff(x * 0.70710678118654752440f));
}

// ---------------- JAX threefry2x32 (20 rounds) ----------------
__host__ __device__ inline void threefry2x32(uint32_t k0, uint32_t k1,
                                             uint32_t x0, uint32_t x1,
                                             uint32_t* o0, uint32_t* o1) {
  uint32_t ks2 = k0 ^ k1 ^ 0x1BD11BDAu;
#define TF_R(r) { x0 += x1; x1 = (x1 << (r)) | (x1 >> (32 - (r))); x1 ^= x0; }
  x0 += k0; x1 += k1;
  TF_R(13) TF_R(15) TF_R(26) TF_R(6)
  x0 += k1; x1 += ks2 + 1u;
  TF_R(17) TF_R(29) TF_R(16) TF_R(24)
  x0 += ks2; x1 += k0 + 2u;
  TF_R(13) TF_R(15) TF_R(26) TF_R(6)
  x0 += k0; x1 += k1 + 3u;
  TF_R(17) TF_R(29) TF_R(16) TF_R(24)
  x0 += k1; x1 += ks2 + 4u;
  TF_R(13) TF_R(15) TF_R(26) TF_R(6)
  x0 += ks2; x1 += k0 + 5u;
#undef TF_R
  *o0 = x0; *o1 = x1;
}

// modern JAX threefry_partitionable: counter (0, idx), bits = o0 ^ o1
__device__ __forceinline__ double gumbel_from(uint32_t k0, uint32_t k1,
                                              uint32_t idx) {
  uint32_t o0, o1;
  threefry2x32(k0, k1, 0u, idx, &o0, &o1);
  uint32_t bits = o0 ^ o1;
  uint32_t ub = (bits >> 9) | 0x3f800000u;
  float f = __uint_as_float(ub) - 1.0f;
  const float tiny = 1.17549435e-38f;
  float u = fmaxf(f + tiny, tiny);
  return -log(-log((double)u));
}

// ---------------- patch pipeline: conv1+BN+GELU+dwconv2+maxpool ----------------
__global__ __launch_bounds__(256) void k_patch(const float* __restrict__ img,
                                               const float* __restrict__ w1, const float* __restrict__ b1,
                                               const float* __restrict__ bng, const float* __restrict__ bnb,
                                               const float* __restrict__ w2, const float* __restrict__ b2) {
  __shared__ float s_in[3 * 16 * 16];
  __shared__ float s_c1[192 * 49];
  const float BN_INV = (float)0.99999500003749968752;
  int p = blockIdx.x;
  int b = p >> 8, g = p & 255, gi = g >> 4, gj = g & 15;
  int tid = threadIdx.x;
  for (int i = tid; i < 3 * 256; i += 256) s_in[i] = 0.f;
  __syncthreads();
  for (int idx = tid; idx < 3 * 196; idx += 256) {
    int c = idx / 196, r = idx % 196, py = r / 14, px = r % 14;
    s_in[c * 256 + (py + 1) * 16 + (px + 1)] =
        img[(((size_t)b * 3 + c) * 224 + gi * 14 + py) * 224 + gj * 14 + px];
  }
  __syncthreads();
  int wave = tid >> 6, lane = tid & 63;
  int y = lane / 7, x = lane - y * 7;
  bool act = lane < 49;
  float in[27];
#pragma unroll
  for (int c = 0; c < 3; ++c)
#pragma unroll
    for (int ky = 0; ky < 3; ++ky)
#pragma unroll
      for (int kx = 0; kx < 3; ++kx)
        in[c * 9 + ky * 3 + kx] = act ? s_in[c * 256 + (2 * y + ky) * 16 + (2 * x + kx)] : 0.f;

  for (int chunk = 0; chunk < 2; ++chunk) {
    int obase = chunk * 192;
    for (int ci = 0; ci < 48; ci += 2) {
      int cl0 = wave * 48 + ci;
      int o0 = obase + cl0, o1 = o0 + 1;
      float a0 = b1[o0], a1 = b1[o1];
      const float* wA = w1 + o0 * 27;
      const float* wB = w1 + o1 * 27;
#pragma unroll
      for (int j = 0; j < 27; ++j) {
        a0 += in[j] * wA[j];
        a1 += in[j] * wB[j];
      }
      a0 = a0 * BN_INV * bng[o0] + bnb[o0];
      a1 = a1 * BN_INV * bng[o1] + bnb[o1];
      if (act) {
        s_c1[cl0 * 49 + lane] = gelu_f(a0);
        s_c1[(cl0 + 1) * 49 + lane] = gelu_f(a1);
      }
    }
    __syncthreads();
    if (tid < 192) {
      int cl = tid, c = obase + cl;
      float wd[9];
#pragma unroll
      for (int j = 0; j < 9; ++j) wd[j] = w2[c * 9 + j];
      float bb2 = b2[c];
      const float* sc = &s_c1[cl * 49];
      float o2[4][4];
#pragma unroll
      for (int yy = 0; yy < 4; ++yy)
#pragma unroll
        for (int xx = 0; xx < 4; ++xx) {
          float a = bb2;
#pragma unroll
          for (int ky = 0; ky < 3; ++ky) {
            int iy = 2 * yy + ky - 1;
            if (iy < 0 || iy >= 7) continue;
#pragma unroll
            for (int kx = 0; kx < 3; ++kx) {
              int ix = 2 * xx + kx - 1;
              if (ix < 0 || ix >= 7) continue;
              a += sc[iy * 7 + ix] * wd[ky * 3 + kx];
            }
          }
          o2[yy][xx] = a;
        }
      float4 r;
      r.x = fmaxf(fmaxf(o2[0][0], o2[0][1]), fmaxf(o2[1][0], o2[1][1]));
      r.y = fmaxf(fmaxf(o2[0][2], o2[0][3]), fmaxf(o2[1][2], o2[1][3]));
      r.z = fmaxf(fmaxf(o2[2][0], o2[2][1]), fmaxf(o2[3][0], o2[3][1]));
      r.w = fmaxf(fmaxf(o2[2][2], o2[2][3]), fmaxf(o2[3][2], o2[3][3]));
      *(float4*)&g_patch[(size_t)p * 1536 + c * 4] = r;
    }
    __syncthreads();
  }
}

// ---------------- generic GEMM (K mult of 384): C = act(A@W + bias) (+resid) ----------------
template <int RPB>
__global__ void k_gemm(const float* __restrict__ W, const float* __restrict__ bias,
                       int selA, int selC, int selR,
                       int M, int K, int N, int act) {
  extern __shared__ float sA[];   // RPB * 384
  const float* A = dev_buf(selA);
  float* C = dev_buf(selC);
  const float* R = (selR >= 0) ? dev_buf(selR) : nullptr;
  int tid = threadIdx.x;
  int bs = blockDim.x;
  int r0 = blockIdx.x * RPB;
  float acc[RPB];
#pragma unroll
  for (int r = 0; r < RPB; ++r) acc[r] = 0.0f;
  const float4 z4 = {0.f, 0.f, 0.f, 0.f};
  for (int k0 = 0; k0 < K; k0 += 384) {
    __syncthreads();
    for (int idx = tid; idx < RPB * 96; idx += bs) {
      int r = idx / 96, q = idx - r * 96;
      int m = r0 + r;
      ((float4*)sA)[idx] = (m < M) ? ((const float4*)(A + (size_t)m * K + k0))[q] : z4;
    }
    __syncthreads();
    const float* Wp = W + (size_t)k0 * N + tid;
    float w0 = Wp[0], w1 = Wp[N], w2 = Wp[2 * (size_t)N], w3 = Wp[3 * (size_t)N];
#pragma unroll 2
    for (int k = 0; k < 384; k += 4) {
      float n0 = 0.f, n1 = 0.f, n2 = 0.f, n3 = 0.f;
      if (k + 4 < 384) {
        const float* Wn = Wp + (size_t)(k + 4) * N;
        n0 = Wn[0]; n1 = Wn[N]; n2 = Wn[2 * (size_t)N]; n3 = Wn[3 * (size_t)N];
      }
#pragma unroll
      for (int r = 0; r < RPB; ++r) {
        float4 a = *(const float4*)&sA[r * 384 + k];
        acc[r] += a.x * w0 + a.y * w1 + a.z * w2 + a.w * w3;
      }
      w0 = n0; w1 = n1; w2 = n2; w3 = n3;
    }
  }
#pragma unroll
  for (int r = 0; r < RPB; ++r) {
    int m = r0 + r;
    if (m >= M) break;
    float v = acc[r];
    if (bias) v += bias[tid];
    if (act == 1) v = gelu_f(v);
    if (R) v += R[(size_t)m * N + tid];
    C[(size_t)m * N + tid] = v;
  }
}

// ---------------- fused LayerNorm + GCN weight projection ----------------
// block per row (b,tt); threads = 384 (6 waves); writes g_xq/g_xk/g_xv
__global__ __launch_bounds__(384) void k_lngcn(const float* __restrict__ gg, const float* __restrict__ bb,
                                               const float* __restrict__ Wq, const float* __restrict__ Wk,
                                               const float* __restrict__ Wv, int t) {
  __shared__ float xn[NDIM];
  __shared__ float wred[6];
  int row = blockIdx.x;          // b*t + tt
  int b = row / t, tt = row - b * t;
  int tid = threadIdx.x;
  int wid = tid >> 6, lane = tid & 63;
  float v = g_x[(size_t)row * NDIM + tid];
  // mean
  float s = v;
#pragma unroll
  for (int off = 32; off > 0; off >>= 1) s += __shfl_xor(s, off);
  if (lane == 0) wred[wid] = s;
  __syncthreads();
  float tot = wred[0] + wred[1] + wred[2] + wred[3] + wred[4] + wred[5];
  float mean = tot * (1.0f / 384.0f);
  __syncthreads();
  // var
  float d = v - mean;
  s = d * d;
#pragma unroll
  for (int off = 32; off > 0; off >>= 1) s += __shfl_xor(s, off);
  if (lane == 0) wred[wid] = s;
  __syncthreads();
  tot = wred[0] + wred[1] + wred[2] + wred[3] + wred[4] + wred[5];
  float var = tot * (1.0f / 384.0f);
  float inv = 1.0f / sqrtf(var + 1e-5f);
  xn[tid] = d * inv * gg[tid] + bb[tid];
  __syncthreads();
  // projection: thread -> (h, d)
  int h = tid / DHD, dd = tid - h * DHD;
  const float* xh = &xn[h * DHD];
  float aq = 0.f, ak = 0.f, av = 0.f;
#pragma unroll 4
  for (int e = 0; e < DHD; ++e) {
    float xv_ = xh[e];
    aq += xv_ * Wq[e * DHD + dd];
    ak += xv_ * Wk[e * DHD + dd];
    av += xv_ * Wv[e * DHD + dd];
  }
  size_t o = ((size_t)(b * NHD + h) * t + tt) * DHD + dd;
  g_xq[o] = aq; g_xk[o] = ak; g_xv[o] = av;
}

// ---------------- q4r/k4r = adj @ xq / adj @ xk, stored (b,t,384) ----------------
__global__ __launch_bounds__(64) void k_adjmm(const int* __restrict__ adji, int use_adj2, int t) {
  __shared__ float arow[256];
  int bid = blockIdx.x;
  int l = bid % t; int h = (bid / t) % NHD; int b = bid / (t * NHD);
  int tid = threadIdx.x;
  for (int s = tid; s < t; s += 64)
    arow[s] = use_adj2 ? g_adj2[((size_t)b * t + l) * t + s] : (float)adji[l * 256 + s];
  __syncthreads();
  if (tid < DHD) {
    const float* xq = g_xq + (size_t)((b * NHD + h) * t) * DHD + tid;
    const float* xk = g_xk + (size_t)((b * NHD + h) * t) * DHD + tid;
    float accq = 0.f, acck = 0.f;
#pragma unroll 4
    for (int s = 0; s < t; ++s) {
      float a = arow[s];
      accq += a * xq[(size_t)s * DHD];
      acck += a * xk[(size_t)s * DHD];
    }
    size_t o = ((size_t)b * t + l) * NDIM + h * DHD + tid;
    g_q4[o] = accq; g_k4[o] = acck;
  }
}

// ---------------- rm0 = gelu([q,k] @ w_kf)  (b*t, 8) ----------------
__global__ __launch_bounds__(64) void k_kf(const float* __restrict__ Wkf) {
  int row = blockIdx.x;
  int tid = threadIdx.x;
  const float* qrow = g_q + (size_t)row * NDIM;
  const float* krow = g_k + (size_t)row * NDIM;
  float accs[8];
#pragma unroll
  for (int j = 0; j < 8; ++j) accs[j] = 0.f;
  for (int m = tid; m < 768; m += 64) {
    float v = (m < 384) ? qrow[m] : krow[m - 384];
    const float* wr = Wkf + (size_t)m * 8;
#pragma unroll
    for (int j = 0; j < 8; ++j) accs[j] += v * wr[j];
  }
#pragma unroll
  for (int j = 0; j < 8; ++j) {
    float a = accs[j];
    for (int off = 32; off > 0; off >>= 1) a += __shfl_xor(a, off);
    if (tid == 0) g_rm0[(size_t)row * 8 + j] = gelu_f(a);
  }
}

// ---------------- rm[b,h,g] = sum_t rm0[b,t,h]*rm0[b,t,g] ----------------
__global__ __launch_bounds__(64) void k_rm(int t) {
  int b = blockIdx.x; int tid = threadIdx.x;
  int h = tid >> 3, g = tid & 7;
  const float* base = g_rm0 + (size_t)b * t * 8;
  float acc = 0.f;
  for (int tt = 0; tt < t; ++tt) acc += base[tt * 8 + h] * base[tt * 8 + g];
  g_rm[b * 64 + tid] = acc;
}

// ---------------- rmd = sigmoid((rm @ wkf2)/sD) ----------------
__global__ void k_rmd(const float* __restrict__ Wp, const float* __restrict__ sDp, int t) {
  int id = blockIdx.x * blockDim.x + threadIdx.x;
  int total = NB * NHD * t;
  if (id >= total) return;
  int s = id % t; int h = (id / t) % NHD; int b = id / (t * NHD);
  const float* rm = g_rm + b * 64 + h * 8;
  float acc = 0.f;
#pragma unroll
  for (int g = 0; g < 8; ++g) acc += rm[g] * Wp[g * t + s];
  float val = acc / sDp[h * t + s];
  g_rmd[(size_t)(b * NHD + h) * t + s] = 1.0f / (1.0f + expf(-val));
}

// ---------------- score = rmd_l * leaky(qk*scale) * rmd_s ----------------
__global__ void k_score(float scale, int t) {
  __shared__ float qs[DHD];
  __shared__ float rl;
  int bid = blockIdx.x;
  int l = bid % t; int h = (bid / t) % NHD; int b = bid / (t * NHD);
  int tid = threadIdx.x;
  if (tid < DHD) qs[tid] = g_q[((size_t)b * t + l) * NDIM + h * DHD + tid];
  if (tid == 0) rl = g_rmd[(size_t)(b * NHD + h) * t + l];
  __syncthreads();
  const float* krow = g_k + ((size_t)b * t + tid) * NDIM + h * DHD;
  float acc = 0.f;
#pragma unroll
  for (int d = 0; d < DHD; ++d) acc += qs[d] * krow[d];
  float v = acc * scale;
  v = (v >= 0.f) ? v : 0.01f * v;
  v = rl * v * g_rmd[(size_t)(b * NHD + h) * t + tid];
  g_score[((size_t)(b * NHD + h) * t + l) * t + tid] = v;
}

// ---------------- fused head-mix + mask + softmax: attn -> g_score2 ----------------
__global__ void k_mixsoft(const float* __restrict__ RM, const int* __restrict__ adji,
                          int use_adj2, int t) {
  extern __shared__ float red2[];
  int bid = blockIdx.x;
  int l = bid % t; int h = (bid / t) % NHD; int b = bid / (t * NHD);
  int tid = threadIdx.x;
  float rm[8];
#pragma unroll
  for (int j = 0; j < 8; ++j) rm[j] = RM[h * 8 + j];
  float acc = 0.f;
#pragma unroll
  for (int j = 0; j < 8; ++j)
    acc += rm[j] * g_score[((size_t)(b * NHD + j) * t + l) * t + tid];
  bool m = use_adj2 ? (g_adj2[((size_t)b * t + l) * t + tid] > 0.f)
                    : (adji[l * 256 + tid] > 0);
  float v = m ? acc : -1e12f;
  red2[tid] = v;
  __syncthreads();
  for (int s = t >> 1; s > 0; s >>= 1) { if (tid < s) red2[tid] = fmaxf(red2[tid], red2[tid + s]); __syncthreads(); }
  float mx = red2[0];
  __syncthreads();
  float e = expf(v - mx);
  red2[tid] = e;
  __syncthreads();
  for (int s = t >> 1; s > 0; s >>= 1) { if (tid < s) red2[tid] += red2[tid + s]; __syncthreads(); }
  g_score2[((size_t)(b * NHD + h) * t + l) * t + tid] = e / red2[0];
}

// ---------------- v4r = attn @ xv, stored (b,t,384) into g_q4 ----------------
__global__ __launch_bounds__(64) void k_attnv(int t) {
  __shared__ float arow[256];
  int bid = blockIdx.x;
  int l = bid % t; int h = (bid / t) % NHD; int b = bid / (t * NHD);
  int tid = threadIdx.x;
  const float* att = g_score2 + ((size_t)(b * NHD + h) * t + l) * t;
  for (int s = tid; s < t; s += 64) arow[s] = att[s];
  __syncthreads();
  if (tid < DHD) {
    const float* xv = g_xv + (size_t)((b * NHD + h) * t) * DHD + tid;
    float acc = 0.f;
#pragma unroll 4
    for (int s = 0; s < t; ++s) acc += arow[s] * xv[(size_t)s * DHD];
    g_q4[((size_t)b * t + l) * NDIM + h * DHD + tid] = acc;
  }
}

// ---------------- gumbel softmax for pooling: tmp[b,j,:] over 256 ----------------
__global__ __launch_bounds__(256) void k_gumbel_pool(uint32_t k0, uint32_t k1) {
  __shared__ double red2[256];
  int bj = blockIdx.x;   // b*64 + j
  int b = bj >> 6, j = bj & 63;
  int tt = threadIdx.x;
  uint32_t n = (uint32_t)bj * 256u + (uint32_t)tt;
  double gum = gumbel_from(k0, k1, n);
  double val = (double)g_logits[((size_t)b * 256 + tt) * 64 + j] + gum;
  red2[tt] = val; __syncthreads();
  for (int s = 128; s > 0; s >>= 1) { if (tt < s) red2[tt] = fmax(red2[tt], red2[tt + s]); __syncthreads(); }
  double mx = red2[0]; __syncthreads();
  double e = exp(val - mx);
  red2[tt] = e; __syncthreads();
  for (int s = 128; s > 0; s >>= 1) { if (tt < s) red2[tt] += red2[tt + s]; __syncthreads(); }
  g_tmp[(size_t)bj * 256 + tt] = (float)(e / red2[0]);
}

// ---------------- xb[b,j,:] = tmp[b,j,:] @ x[b,:,:] ----------------
__global__ __launch_bounds__(384) void k_poolx() {
  __shared__ float trow[256];
  int bj = blockIdx.x; int b = bj >> 6;
  int tid = threadIdx.x;
  if (tid < 256) trow[tid] = g_tmp[(size_t)bj * 256 + tid];
  __syncthreads();
  float acc = 0.f;
  const float* xb = g_x + (size_t)b * 256 * NDIM + tid;
  for (int tt = 0; tt < 256; ++tt) acc += trow[tt] * xb[(size_t)tt * NDIM];
  g_xb[(size_t)bj * NDIM + tid] = acc;
}

__global__ void k_copyx(int n) {
  int i = blockIdx.x * blockDim.x + threadIdx.x;
  if (i < n) g_x[i] = g_xb[i];
}

// ---------------- e1[b,l,t] = sum_s tmp[b,l,s]*adj[s,t] ----------------
__global__ __launch_bounds__(256) void k_pooladj1(const int* __restrict__ adji) {
  __shared__ float trow[256];
  int bl = blockIdx.x;
  int tid = threadIdx.x;
  trow[tid] = g_tmp[(size_t)bl * 256 + tid];
  __syncthreads();
  float acc = 0.f;
  for (int s = 0; s < 256; ++s) acc += trow[s] * (float)adji[s * 256 + tid];
  g_e1[(size_t)bl * 256 + tid] = acc;
}

// ---------------- adj2[b,l,m] = sum_t e1[b,l,t]*tmp[b,m,t] ----------------
__global__ __launch_bounds__(64) void k_pooladj2() {
  __shared__ float erow[256];
  int bl = blockIdx.x; int b = bl >> 6;
  int tid = threadIdx.x;
  for (int s = tid; s < 256; s += 64) erow[s] = g_e1[(size_t)bl * 256 + s];
  __syncthreads();
  const float* tm = g_tmp + ((size_t)b * 64 + tid) * 256;
  float acc = 0.f;
  for (int s = 0; s < 256; ++s) acc += erow[s] * tm[s];
  g_adj2[(size_t)bl * 64 + tid] = acc;
}

// ---------------- final logits: x @ upoolout_w + b ----------------
__global__ __launch_bounds__(64) void k_outlogits(const float* __restrict__ w, const float* __restrict__ bias) {
  int row = blockIdx.x;
  int tid = threadIdx.x;
  const float* x = g_x + (size_t)row * NDIM;
  float acc = 0.f;
  for (int c = tid; c < NDIM; c += 64) acc += x[c] * w[c];
  for (int off = 32; off > 0; off >>= 1) acc += __shfl_xor(acc, off);
  if (tid == 0) g_lg2[row] = acc + bias[0];
}

// ---------------- final gumbel softmax + weighted sum -> out ----------------
__global__ __launch_bounds__(384) void k_final(uint32_t k0, uint32_t k1, float* __restrict__ out) {
  __shared__ double sv[64];
  __shared__ double sp[64];
  int b = blockIdx.x;
  int tid = threadIdx.x;
  if (tid < 64) {
    uint32_t n = (uint32_t)(b * 64 + tid);
    sv[tid] = (double)g_lg2[b * 64 + tid] + gumbel_from(k0, k1, n);
  }
  __syncthreads();
  double mx = -1e30;
  for (int i2 = 0; i2 < 64; ++i2) mx = fmax(mx, sv[i2]);
  if (tid < 64) sp[tid] = exp(sv[tid] - mx);
  __syncthreads();
  double sum = 0.;
  for (int i2 = 0; i2 < 64; ++i2) sum += sp[i2];
  float acc = 0.f;
  const float* xb = g_x + (size_t)b * 64 * NDIM + tid;
  for (int tt = 0; tt < 64; ++tt) acc += (float)(sp[tt] / sum) * xb[(size_t)tt * NDIM];
  out[(size_t)b * NDIM + tid] = acc;
}

// ---------------- host ----------------
extern "C" void kernel_launch(void* const* d_in, const int* in_sizes, int n_in,
                              void* d_out, int out_size, void* d_ws, size_t ws_size,
                              hipStream_t stream) {
  const float* img = (const float*)d_in[0];
  const int* adj = (const int*)d_in[1];
  const float* ln_g = (const float*)d_in[2];
  const float* ln_b = (const float*)d_in[3];
  const float* gcn_wq = (const float*)d_in[4];
  const float* gcn_wk = (const float*)d_in[5];
  const float* gcn_wv = (const float*)d_in[6];
  const float* wq = (const float*)d_in[7];
  const float* wk = (const float*)d_in[8];
  const float* wv = (const float*)d_in[9];
  const float* w_kf = (const float*)d_in[10];
  const float* w_kf2 = (const float*)d_in[11];
  const float* w_kf3 = (const float*)d_in[12];
  const float* sD = (const float*)d_in[13];
  const float* sD2 = (const float*)d_in[14];
  const float* randmat = (const float*)d_in[15];
  const float* conv1_w = (const float*)d_in[16];
  const float* conv1_b = (const float*)d_in[17];
  const float* bn_g = (const float*)d_in[18];
  const float* bn_b = (const float*)d_in[19];
  const float* conv2_w = (const float*)d_in[20];
  const float* conv2_b = (const float*)d_in[21];
  const float* emb_w = (const float*)d_in[22];
  const float* emb_b = (const float*)d_in[23];
  const float* upool_w = (const float*)d_in[24];
  const float* upool_b = (const float*)d_in[25];
  const float* upoolout_w = (const float*)d_in[26];
  const float* upoolout_b = (const float*)d_in[27];
  float* out = (float*)d_out;

  uint32_t k2a, k2b, k99a, k99b;
  threefry2x32(0u, 42u, 0u, 2u, &k2a, &k2b);
  threefry2x32(0u, 42u, 0u, 99u, &k99a, &k99b);

  const float SCALE = (float)(1.0 / sqrt(384.0));

  k_patch<<<2048, 256, 0, stream>>>(img, conv1_w, conv1_b, bn_g, bn_b, conv2_w, conv2_b);
  k_gemm<4><<<512, 384, 4 * 384 * sizeof(float), stream>>>(
      emb_w, emb_b, SEL_PATCH, SEL_X, -1, 2048, 1536, 384, 0);

  auto attention = [&](int i, int t, int label) {
    int rows = NB * t;
    int bht = NB * NHD * t;
    int use_adj2 = (t == 64) ? 1 : 0;
    k_lngcn<<<rows, 384, 0, stream>>>(ln_g + i * 384, ln_b + i * 384,
                                      gcn_wq + i * 2304, gcn_wk + i * 2304,
                                      gcn_wv + i * 2304, t);
    k_adjmm<<<bht, 64, 0, stream>>>(adj, use_adj2, t);
    if (rows == 2048) {
      k_gemm<4><<<512, 384, 4 * 384 * sizeof(float), stream>>>(
          wq + i * 147456, nullptr, SEL_Q4, SEL_Q, -1, rows, 384, 384, 0);
      k_gemm<4><<<512, 384, 4 * 384 * sizeof(float), stream>>>(
          wk + i * 147456, nullptr, SEL_K4, SEL_K, -1, rows, 384, 384, 0);
    } else {
      k_gemm<2><<<256, 384, 2 * 384 * sizeof(float), stream>>>(
          wq + i * 147456, nullptr, SEL_Q4, SEL_Q, -1, rows, 384, 384, 0);
      k_gemm<2><<<256, 384, 2 * 384 * sizeof(float), stream>>>(
          wk + i * 147456, nullptr, SEL_K4, SEL_K, -1, rows, 384, 384, 0);
    }
    k_kf<<<rows, 64, 0, stream>>>(w_kf + i * 6144);
    k_rm<<<NB, 64, 0, stream>>>(t);
    const float* Wp = label ? (w_kf3 + i * 512) : (w_kf2 + i * 2048);
    const float* sDp = label ? (sD2 + i * 512) : (sD + i * 2048);
    int totr = NB * NHD * t;
    k_rmd<<<(totr + 255) / 256, 256, 0, stream>>>(Wp, sDp, t);
    k_score<<<bht, t, 0, stream>>>(SCALE, t);
    k_mixsoft<<<bht, t, t * sizeof(float), stream>>>(randmat + i * 64, adj, use_adj2, t);
    k_attnv<<<bht, 64, 0, stream>>>(t);
    if (rows == 2048) {
      k_gemm<4><<<512, 384, 4 * 384 * sizeof(float), stream>>>(
          wv + i * 147456, nullptr, SEL_Q4, SEL_X, SEL_X, rows, 384, 384, 1);
    } else {
      k_gemm<2><<<256, 384, 2 * 384 * sizeof(float), stream>>>(
          wv + i * 147456, nullptr, SEL_Q4, SEL_X, SEL_X, rows, 384, 384, 1);
    }
  };

  attention(0, 256, 0);
  attention(1, 256, 0);

  // pooling at i==2
  k_gemm<2><<<1024, 64, 2 * 384 * sizeof(float), stream>>>(
      upool_w, upool_b, SEL_X, SEL_LOGITS, -1, 2048, 384, 64, 0);
  k_gumbel_pool<<<512, 256, 0, stream>>>(k2a, k2b);
  k_poolx<<<512, 384, 0, stream>>>();
  k_copyx<<<(NB * 64 * NDIM + 255) / 256, 256, 0, stream>>>(NB * 64 * NDIM);
  k_pooladj1<<<512, 256, 0, stream>>>(adj);
  k_pooladj2<<<512, 64, 0, stream>>>();

  attention(2, 64, 1);
  attention(3, 64, 1);

  k_outlogits<<<512, 64, 0, stream>>>(upoolout_w, upoolout_b);
  k_final<<<8, 384, 0, stream>>>(k99a, k99b, out);
}

// Round 9
// 1256.928 us; speedup vs baseline: 2.8315x; 1.2026x over previous
//
#include <hip/hip_runtime.h>
#include <stdint.h>
#include <math.h>

#define NB 8
#define NDIM 384
#define NHD 8
#define DHD 48

// ---------------- persistent device buffers (f32) ----------------
__device__ float g_patch[2048 * 1536];
__device__ float g_x[NB * 256 * NDIM];
__device__ float g_xb[NB * 64 * NDIM];
__device__ float g_xq[NB * NHD * 256 * DHD];
__device__ float g_xk[NB * NHD * 256 * DHD];
__device__ float g_xv[NB * NHD * 256 * DHD];
__device__ float g_q4[NB * 256 * NDIM];
__device__ float g_k4[NB * 256 * NDIM];
__device__ float g_q[NB * 256 * NDIM];
__device__ float g_k[NB * 256 * NDIM];
__device__ float g_rm0[NB * 256 * NHD];
__device__ float g_rm[NB * 64];
__device__ float g_rmd[NB * NHD * 256];
__device__ float g_score[NB * NHD * 256 * 256];
__device__ float g_score2[NB * NHD * 256 * 256];
__device__ float g_logits[NB * 256 * 64];
__device__ float g_tmp[NB * 64 * 256];
__device__ float g_e1[NB * 64 * 256];
__device__ float g_adj2[NB * 64 * 64];
__device__ float g_lg2[NB * 64];

__device__ __forceinline__ float* dev_buf(int s) {
  switch (s) {
    case 0: return g_patch;
    case 1: return g_x;
    case 2: return g_q4;
    case 3: return g_k4;
    case 4: return g_q;
    case 5: return g_k;
    case 6: return g_logits;
    default: return nullptr;
  }
}
#define SEL_PATCH 0
#define SEL_X 1
#define SEL_Q4 2
#define SEL_K4 3
#define SEL_Q 4
#define SEL_K 5
#define SEL_LOGITS 6

__device__ __forceinline__ float gelu_f(float x) {
  return 0.5f * x * (1.0f + erff(x * 0.70710678118654752440f));
}

// ---------------- JAX threefry2x32 (20 rounds) ----------------
__host__ __device__ inline void threefry2x32(uint32_t k0, uint32_t k1,
                                             uint32_t x0, uint32_t x1,
                                             uint32_t* o0, uint32_t* o1) {
  uint32_t ks2 = k0 ^ k1 ^ 0x1BD11BDAu;
#define TF_R(r) { x0 += x1; x1 = (x1 << (r)) | (x1 >> (32 - (r))); x1 ^= x0; }
  x0 += k0; x1 += k1;
  TF_R(13) TF_R(15) TF_R(26) TF_R(6)
  x0 += k1; x1 += ks2 + 1u;
  TF_R(17) TF_R(29) TF_R(16) TF_R(24)
  x0 += ks2; x1 += k0 + 2u;
  TF_R(13) TF_R(15) TF_R(26) TF_R(6)
  x0 += k0; x1 += k1 + 3u;
  TF_R(17) TF_R(29) TF_R(16) TF_R(24)
  x0 += k1; x1 += ks2 + 4u;
  TF_R(13) TF_R(15) TF_R(26) TF_R(6)
  x0 += ks2; x1 += k0 + 5u;
#undef TF_R
  *o0 = x0; *o1 = x1;
}

// modern JAX threefry_partitionable: counter (0, idx), bits = o0 ^ o1
__device__ __forceinline__ double gumbel_from(uint32_t k0, uint32_t k1,
                                              uint32_t idx) {
  uint32_t o0, o1;
  threefry2x32(k0, k1, 0u, idx, &o0, &o1);
  uint32_t bits = o0 ^ o1;
  uint32_t ub = (bits >> 9) | 0x3f800000u;
  float f = __uint_as_float(ub) - 1.0f;
  const float tiny = 1.17549435e-38f;
  float u = fmaxf(f + tiny, tiny);
  return -log(-log((double)u));
}

// ---------------- patch pipeline: conv1+BN+GELU+dwconv2+maxpool ----------------
// 96-channel chunks (22KB LDS -> 7 blocks/CU); conv1 4-way unrolled.
__global__ __launch_bounds__(256) void k_patch(const float* __restrict__ img,
                                               const float* __restrict__ w1, const float* __restrict__ b1,
                                               const float* __restrict__ bng, const float* __restrict__ bnb,
                                               const float* __restrict__ w2, const float* __restrict__ b2) {
  __shared__ float s_in[3 * 16 * 16];
  __shared__ float s_c1[96 * 49];
  const float BN_INV = (float)0.99999500003749968752;
  int p = blockIdx.x;
  int b = p >> 8, g = p & 255, gi = g >> 4, gj = g & 15;
  int tid = threadIdx.x;
  for (int i = tid; i < 3 * 256; i += 256) s_in[i] = 0.f;
  __syncthreads();
  for (int idx = tid; idx < 3 * 196; idx += 256) {
    int c = idx / 196, r = idx % 196, py = r / 14, px = r % 14;
    s_in[c * 256 + (py + 1) * 16 + (px + 1)] =
        img[(((size_t)b * 3 + c) * 224 + gi * 14 + py) * 224 + gj * 14 + px];
  }
  __syncthreads();
  int wave = tid >> 6, lane = tid & 63;
  int y = lane / 7, x = lane - y * 7;
  bool act = lane < 49;
  float in[27];
#pragma unroll
  for (int c = 0; c < 3; ++c)
#pragma unroll
    for (int ky = 0; ky < 3; ++ky)
#pragma unroll
      for (int kx = 0; kx < 3; ++kx)
        in[c * 9 + ky * 3 + kx] = act ? s_in[c * 256 + (2 * y + ky) * 16 + (2 * x + kx)] : 0.f;

  for (int chunk = 0; chunk < 4; ++chunk) {
    int obase = chunk * 96;
    // conv1: 24 channels per wave, 4-way unrolled
    for (int ci = 0; ci < 24; ci += 4) {
      int cl0 = wave * 24 + ci;
      int o0 = obase + cl0;
      float a0 = b1[o0], a1 = b1[o0 + 1], a2 = b1[o0 + 2], a3 = b1[o0 + 3];
      const float* wA = w1 + o0 * 27;
#pragma unroll
      for (int j = 0; j < 27; ++j) {
        float ij = in[j];
        a0 += ij * wA[j];
        a1 += ij * wA[27 + j];
        a2 += ij * wA[54 + j];
        a3 += ij * wA[81 + j];
      }
      a0 = a0 * BN_INV * bng[o0] + bnb[o0];
      a1 = a1 * BN_INV * bng[o0 + 1] + bnb[o0 + 1];
      a2 = a2 * BN_INV * bng[o0 + 2] + bnb[o0 + 2];
      a3 = a3 * BN_INV * bng[o0 + 3] + bnb[o0 + 3];
      if (act) {
        s_c1[cl0 * 49 + lane] = gelu_f(a0);
        s_c1[(cl0 + 1) * 49 + lane] = gelu_f(a1);
        s_c1[(cl0 + 2) * 49 + lane] = gelu_f(a2);
        s_c1[(cl0 + 3) * 49 + lane] = gelu_f(a3);
      }
    }
    __syncthreads();
    if (tid < 96) {
      int cl = tid, c = obase + cl;
      float wd[9];
#pragma unroll
      for (int j = 0; j < 9; ++j) wd[j] = w2[c * 9 + j];
      float bb2 = b2[c];
      const float* sc = &s_c1[cl * 49];
      float o2[4][4];
#pragma unroll
      for (int yy = 0; yy < 4; ++yy)
#pragma unroll
        for (int xx = 0; xx < 4; ++xx) {
          float a = bb2;
#pragma unroll
          for (int ky = 0; ky < 3; ++ky) {
            int iy = 2 * yy + ky - 1;
            if (iy < 0 || iy >= 7) continue;
#pragma unroll
            for (int kx = 0; kx < 3; ++kx) {
              int ix = 2 * xx + kx - 1;
              if (ix < 0 || ix >= 7) continue;
              a += sc[iy * 7 + ix] * wd[ky * 3 + kx];
            }
          }
          o2[yy][xx] = a;
        }
      float4 r;
      r.x = fmaxf(fmaxf(o2[0][0], o2[0][1]), fmaxf(o2[1][0], o2[1][1]));
      r.y = fmaxf(fmaxf(o2[0][2], o2[0][3]), fmaxf(o2[1][2], o2[1][3]));
      r.z = fmaxf(fmaxf(o2[2][0], o2[2][1]), fmaxf(o2[3][0], o2[3][1]));
      r.w = fmaxf(fmaxf(o2[2][2], o2[2][3]), fmaxf(o2[3][2], o2[3][3]));
      *(float4*)&g_patch[(size_t)p * 1536 + c * 4] = r;
    }
    __syncthreads();
  }
}

// ---------------- generic GEMM (K mult of 384): C = act(A@W + bias) (+resid) ----------------
template <int RPB>
__global__ void k_gemm(const float* __restrict__ W, const float* __restrict__ bias,
                       int selA, int selC, int selR,
                       int M, int K, int N, int act) {
  extern __shared__ float sA[];   // RPB * 384
  const float* A = dev_buf(selA);
  float* C = dev_buf(selC);
  const float* R = (selR >= 0) ? dev_buf(selR) : nullptr;
  int tid = threadIdx.x;
  int bs = blockDim.x;
  int r0 = blockIdx.x * RPB;
  float acc[RPB];
#pragma unroll
  for (int r = 0; r < RPB; ++r) acc[r] = 0.0f;
  const float4 z4 = {0.f, 0.f, 0.f, 0.f};
  for (int k0 = 0; k0 < K; k0 += 384) {
    __syncthreads();
    for (int idx = tid; idx < RPB * 96; idx += bs) {
      int r = idx / 96, q = idx - r * 96;
      int m = r0 + r;
      ((float4*)sA)[idx] = (m < M) ? ((const float4*)(A + (size_t)m * K + k0))[q] : z4;
    }
    __syncthreads();
    const float* Wp = W + (size_t)k0 * N + tid;
    float w0 = Wp[0], w1 = Wp[N], w2 = Wp[2 * (size_t)N], w3 = Wp[3 * (size_t)N];
#pragma unroll 2
    for (int k = 0; k < 384; k += 4) {
      float n0 = 0.f, n1 = 0.f, n2 = 0.f, n3 = 0.f;
      if (k + 4 < 384) {
        const float* Wn = Wp + (size_t)(k + 4) * N;
        n0 = Wn[0]; n1 = Wn[N]; n2 = Wn[2 * (size_t)N]; n3 = Wn[3 * (size_t)N];
      }
#pragma unroll
      for (int r = 0; r < RPB; ++r) {
        float4 a = *(const float4*)&sA[r * 384 + k];
        acc[r] += a.x * w0 + a.y * w1 + a.z * w2 + a.w * w3;
      }
      w0 = n0; w1 = n1; w2 = n2; w3 = n3;
    }
  }
#pragma unroll
  for (int r = 0; r < RPB; ++r) {
    int m = r0 + r;
    if (m >= M) break;
    float v = acc[r];
    if (bias) v += bias[tid];
    if (act == 1) v = gelu_f(v);
    if (R) v += R[(size_t)m * N + tid];
    C[(size_t)m * N + tid] = v;
  }
}

// ---------------- fused LayerNorm + GCN weight projection ----------------
__global__ __launch_bounds__(384) void k_lngcn(const float* __restrict__ gg, const float* __restrict__ bb,
                                               const float* __restrict__ Wq, const float* __restrict__ Wk,
                                               const float* __restrict__ Wv, int t) {
  __shared__ float xn[NDIM];
  __shared__ float wred[6];
  int row = blockIdx.x;          // b*t + tt
  int b = row / t, tt = row - b * t;
  int tid = threadIdx.x;
  int wid = tid >> 6, lane = tid & 63;
  float v = g_x[(size_t)row * NDIM + tid];
  float s = v;
#pragma unroll
  for (int off = 32; off > 0; off >>= 1) s += __shfl_xor(s, off);
  if (lane == 0) wred[wid] = s;
  __syncthreads();
  float tot = wred[0] + wred[1] + wred[2] + wred[3] + wred[4] + wred[5];
  float mean = tot * (1.0f / 384.0f);
  __syncthreads();
  float d = v - mean;
  s = d * d;
#pragma unroll
  for (int off = 32; off > 0; off >>= 1) s += __shfl_xor(s, off);
  if (lane == 0) wred[wid] = s;
  __syncthreads();
  tot = wred[0] + wred[1] + wred[2] + wred[3] + wred[4] + wred[5];
  float var = tot * (1.0f / 384.0f);
  float inv = 1.0f / sqrtf(var + 1e-5f);
  xn[tid] = d * inv * gg[tid] + bb[tid];
  __syncthreads();
  int h = tid / DHD, dd = tid - h * DHD;
  const float* xh = &xn[h * DHD];
  float aq = 0.f, ak = 0.f, av = 0.f;
#pragma unroll 4
  for (int e = 0; e < DHD; ++e) {
    float xv_ = xh[e];
    aq += xv_ * Wq[e * DHD + dd];
    ak += xv_ * Wk[e * DHD + dd];
    av += xv_ * Wv[e * DHD + dd];
  }
  size_t o = ((size_t)(b * NHD + h) * t + tt) * DHD + dd;
  g_xq[o] = aq; g_xk[o] = ak; g_xv[o] = av;
}

// ---------------- q4r/k4r = adj @ xq / adj @ xk — 4 rows per block ----------------
__global__ __launch_bounds__(64) void k_adjmm(const int* __restrict__ adji, int use_adj2, int t) {
  __shared__ float arow[4][256];
  int bid = blockIdx.x;
  int nt = t >> 2;
  int lt = bid % nt; int h = (bid / nt) % NHD; int b = bid / (nt * NHD);
  int l0 = lt * 4;
  int tid = threadIdx.x;
  for (int idx = tid; idx < 4 * t; idx += 64) {
    int r = idx / t, s2 = idx - r * t;
    arow[r][s2] = use_adj2 ? g_adj2[((size_t)b * t + l0 + r) * t + s2]
                           : (float)adji[(l0 + r) * 256 + s2];
  }
  __syncthreads();
  if (tid < DHD) {
    const float* xq = g_xq + (size_t)((b * NHD + h) * t) * DHD + tid;
    const float* xk = g_xk + (size_t)((b * NHD + h) * t) * DHD + tid;
    float aq[4] = {0.f, 0.f, 0.f, 0.f}, ak[4] = {0.f, 0.f, 0.f, 0.f};
    for (int s2 = 0; s2 < t; ++s2) {
      float xqv = xq[(size_t)s2 * DHD];
      float xkv = xk[(size_t)s2 * DHD];
#pragma unroll
      for (int r = 0; r < 4; ++r) {
        aq[r] += arow[r][s2] * xqv;
        ak[r] += arow[r][s2] * xkv;
      }
    }
#pragma unroll
    for (int r = 0; r < 4; ++r) {
      size_t o = ((size_t)b * t + l0 + r) * NDIM + h * DHD + tid;
      g_q4[o] = aq[r]; g_k4[o] = ak[r];
    }
  }
}

// ---------------- rm0 = gelu([q,k] @ w_kf)  (b*t, 8) ----------------
__global__ __launch_bounds__(64) void k_kf(const float* __restrict__ Wkf) {
  int row = blockIdx.x;
  int tid = threadIdx.x;
  const float* qrow = g_q + (size_t)row * NDIM;
  const float* krow = g_k + (size_t)row * NDIM;
  float accs[8];
#pragma unroll
  for (int j = 0; j < 8; ++j) accs[j] = 0.f;
  for (int m = tid; m < 768; m += 64) {
    float v = (m < 384) ? qrow[m] : krow[m - 384];
    const float* wr = Wkf + (size_t)m * 8;
#pragma unroll
    for (int j = 0; j < 8; ++j) accs[j] += v * wr[j];
  }
#pragma unroll
  for (int j = 0; j < 8; ++j) {
    float a = accs[j];
    for (int off = 32; off > 0; off >>= 1) a += __shfl_xor(a, off);
    if (tid == 0) g_rm0[(size_t)row * 8 + j] = gelu_f(a);
  }
}

// ---------------- rm[b,h,g] = sum_t rm0[b,t,h]*rm0[b,t,g] ----------------
__global__ __launch_bounds__(64) void k_rm(int t) {
  int b = blockIdx.x; int tid = threadIdx.x;
  int h = tid >> 3, g = tid & 7;
  const float* base = g_rm0 + (size_t)b * t * 8;
  float acc = 0.f;
  for (int tt = 0; tt < t; ++tt) acc += base[tt * 8 + h] * base[tt * 8 + g];
  g_rm[b * 64 + tid] = acc;
}

// ---------------- rmd = sigmoid((rm @ wkf2)/sD) ----------------
__global__ void k_rmd(const float* __restrict__ Wp, const float* __restrict__ sDp, int t) {
  int id = blockIdx.x * blockDim.x + threadIdx.x;
  int total = NB * NHD * t;
  if (id >= total) return;
  int s = id % t; int h = (id / t) % NHD; int b = id / (t * NHD);
  const float* rm = g_rm + b * 64 + h * 8;
  float acc = 0.f;
#pragma unroll
  for (int g = 0; g < 8; ++g) acc += rm[g] * Wp[g * t + s];
  float val = acc / sDp[h * t + s];
  g_rmd[(size_t)(b * NHD + h) * t + s] = 1.0f / (1.0f + expf(-val));
}

// ---------------- score: 4 q-rows per block; K row in registers ----------------
__global__ void k_score(float scale, int t) {
  __shared__ float qs[4][DHD];
  __shared__ float rl[4];
  int bid = blockIdx.x;
  int nt = t >> 2;
  int lt = bid % nt; int h = (bid / nt) % NHD; int b = bid / (nt * NHD);
  int l0 = lt * 4;
  int tid = threadIdx.x;
  for (int idx = tid; idx < 4 * DHD; idx += t) {
    int r = idx / DHD, d = idx - r * DHD;
    qs[r][d] = g_q[((size_t)b * t + l0 + r) * NDIM + h * DHD + d];
  }
  if (tid < 4) rl[tid] = g_rmd[(size_t)(b * NHD + h) * t + l0 + tid];
  __syncthreads();
  const float* krow = g_k + ((size_t)b * t + tid) * NDIM + h * DHD;
  float4 kr[12];
#pragma unroll
  for (int j = 0; j < 12; ++j) kr[j] = *(const float4*)&krow[j * 4];
  float rmd_s = g_rmd[(size_t)(b * NHD + h) * t + tid];
#pragma unroll
  for (int r = 0; r < 4; ++r) {
    float acc = 0.f;
#pragma unroll
    for (int j = 0; j < 12; ++j) {
      float4 qq = *(const float4*)&qs[r][j * 4];
      acc += kr[j].x * qq.x + kr[j].y * qq.y + kr[j].z * qq.z + kr[j].w * qq.w;
    }
    float v = acc * scale;
    v = (v >= 0.f) ? v : 0.01f * v;
    v = rl[r] * v * rmd_s;
    g_score[((size_t)(b * NHD + h) * t + l0 + r) * t + tid] = v;
  }
}

// ---------------- fused head-mix + mask + softmax: attn -> g_score2 ----------------
__global__ void k_mixsoft(const float* __restrict__ RM, const int* __restrict__ adji,
                          int use_adj2, int t) {
  extern __shared__ float red2[];
  int bid = blockIdx.x;
  int l = bid % t; int h = (bid / t) % NHD; int b = bid / (t * NHD);
  int tid = threadIdx.x;
  float rm[8];
#pragma unroll
  for (int j = 0; j < 8; ++j) rm[j] = RM[h * 8 + j];
  float acc = 0.f;
#pragma unroll
  for (int j = 0; j < 8; ++j)
    acc += rm[j] * g_score[((size_t)(b * NHD + j) * t + l) * t + tid];
  bool m = use_adj2 ? (g_adj2[((size_t)b * t + l) * t + tid] > 0.f)
                    : (adji[l * 256 + tid] > 0);
  float v = m ? acc : -1e12f;
  red2[tid] = v;
  __syncthreads();
  for (int s = t >> 1; s > 0; s >>= 1) { if (tid < s) red2[tid] = fmaxf(red2[tid], red2[tid + s]); __syncthreads(); }
  float mx = red2[0];
  __syncthreads();
  float e = expf(v - mx);
  red2[tid] = e;
  __syncthreads();
  for (int s = t >> 1; s > 0; s >>= 1) { if (tid < s) red2[tid] += red2[tid + s]; __syncthreads(); }
  g_score2[((size_t)(b * NHD + h) * t + l) * t + tid] = e / red2[0];
}

// ---------------- v4r = attn @ xv — 4 rows per block ----------------
__global__ __launch_bounds__(64) void k_attnv(int t) {
  __shared__ float arow[4][256];
  int bid = blockIdx.x;
  int nt = t >> 2;
  int lt = bid % nt; int h = (bid / nt) % NHD; int b = bid / (nt * NHD);
  int l0 = lt * 4;
  int tid = threadIdx.x;
  for (int idx = tid; idx < 4 * t; idx += 64) {
    int r = idx / t, s2 = idx - r * t;
    arow[r][s2] = g_score2[((size_t)(b * NHD + h) * t + l0 + r) * t + s2];
  }
  __syncthreads();
  if (tid < DHD) {
    const float* xv = g_xv + (size_t)((b * NHD + h) * t) * DHD + tid;
    float acc[4] = {0.f, 0.f, 0.f, 0.f};
    for (int s2 = 0; s2 < t; ++s2) {
      float xvv = xv[(size_t)s2 * DHD];
#pragma unroll
      for (int r = 0; r < 4; ++r) acc[r] += arow[r][s2] * xvv;
    }
#pragma unroll
    for (int r = 0; r < 4; ++r)
      g_q4[((size_t)b * t + l0 + r) * NDIM + h * DHD + tid] = acc[r];
  }
}

// ---------------- gumbel softmax for pooling: tmp[b,j,:] over 256 ----------------
__global__ __launch_bounds__(256) void k_gumbel_pool(uint32_t k0, uint32_t k1) {
  __shared__ double red2[256];
  int bj = blockIdx.x;   // b*64 + j
  int b = bj >> 6, j = bj & 63;
  int tt = threadIdx.x;
  uint32_t n = (uint32_t)bj * 256u + (uint32_t)tt;
  double gum = gumbel_from(k0, k1, n);
  double val = (double)g_logits[((size_t)b * 256 + tt) * 64 + j] + gum;
  red2[tt] = val; __syncthreads();
  for (int s = 128; s > 0; s >>= 1) { if (tt < s) red2[tt] = fmax(red2[tt], red2[tt + s]); __syncthreads(); }
  double mx = red2[0]; __syncthreads();
  double e = exp(val - mx);
  red2[tt] = e; __syncthreads();
  for (int s = 128; s > 0; s >>= 1) { if (tt < s) red2[tt] += red2[tt + s]; __syncthreads(); }
  g_tmp[(size_t)bj * 256 + tt] = (float)(e / red2[0]);
}

// ---------------- xb[b,j,:] = tmp[b,j,:] @ x[b,:,:] ----------------
__global__ __launch_bounds__(384) void k_poolx() {
  __shared__ float trow[256];
  int bj = blockIdx.x; int b = bj >> 6;
  int tid = threadIdx.x;
  if (tid < 256) trow[tid] = g_tmp[(size_t)bj * 256 + tid];
  __syncthreads();
  float acc = 0.f;
  const float* xb = g_x + (size_t)b * 256 * NDIM + tid;
  for (int tt = 0; tt < 256; ++tt) acc += trow[tt] * xb[(size_t)tt * NDIM];
  g_xb[(size_t)bj * NDIM + tid] = acc;
}

__global__ void k_copyx(int n) {
  int i = blockIdx.x * blockDim.x + threadIdx.x;
  if (i < n) g_x[i] = g_xb[i];
}

// ---------------- e1[b,l,t] = sum_s tmp[b,l,s]*adj[s,t] ----------------
__global__ __launch_bounds__(256) void k_pooladj1(const int* __restrict__ adji) {
  __shared__ float trow[256];
  int bl = blockIdx.x;
  int tid = threadIdx.x;
  trow[tid] = g_tmp[(size_t)bl * 256 + tid];
  __syncthreads();
  float acc = 0.f;
  for (int s = 0; s < 256; ++s) acc += trow[s] * (float)adji[s * 256 + tid];
  g_e1[(size_t)bl * 256 + tid] = acc;
}

// ---------------- adj2[b,l,m] = sum_t e1[b,l,t]*tmp[b,m,t] ----------------
__global__ __launch_bounds__(64) void k_pooladj2() {
  __shared__ float erow[256];
  int bl = blockIdx.x; int b = bl >> 6;
  int tid = threadIdx.x;
  for (int s = tid; s < 256; s += 64) erow[s] = g_e1[(size_t)bl * 256 + s];
  __syncthreads();
  const float* tm = g_tmp + ((size_t)b * 64 + tid) * 256;
  float acc = 0.f;
  for (int s = 0; s < 256; ++s) acc += erow[s] * tm[s];
  g_adj2[(size_t)bl * 64 + tid] = acc;
}

// ---------------- final logits: x @ upoolout_w + b ----------------
__global__ __launch_bounds__(64) void k_outlogits(const float* __restrict__ w, const float* __restrict__ bias) {
  int row = blockIdx.x;
  int tid = threadIdx.x;
  const float* x = g_x + (size_t)row * NDIM;
  float acc = 0.f;
  for (int c = tid; c < NDIM; c += 64) acc += x[c] * w[c];
  for (int off = 32; off > 0; off >>= 1) acc += __shfl_xor(acc, off);
  if (tid == 0) g_lg2[row] = acc + bias[0];
}

// ---------------- final gumbel softmax + weighted sum -> out ----------------
__global__ __launch_bounds__(384) void k_final(uint32_t k0, uint32_t k1, float* __restrict__ out) {
  __shared__ double sv[64];
  __shared__ double sp[64];
  int b = blockIdx.x;
  int tid = threadIdx.x;
  if (tid < 64) {
    uint32_t n = (uint32_t)(b * 64 + tid);
    sv[tid] = (double)g_lg2[b * 64 + tid] + gumbel_from(k0, k1, n);
  }
  __syncthreads();
  double mx = -1e30;
  for (int i2 = 0; i2 < 64; ++i2) mx = fmax(mx, sv[i2]);
  if (tid < 64) sp[tid] = exp(sv[tid] - mx);
  __syncthreads();
  double sum = 0.;
  for (int i2 = 0; i2 < 64; ++i2) sum += sp[i2];
  float acc = 0.f;
  const float* xb = g_x + (size_t)b * 64 * NDIM + tid;
  for (int tt = 0; tt < 64; ++tt) acc += (float)(sp[tt] / sum) * xb[(size_t)tt * NDIM];
  out[(size_t)b * NDIM + tid] = acc;
}

// ---------------- host ----------------
extern "C" void kernel_launch(void* const* d_in, const int* in_sizes, int n_in,
                              void* d_out, int out_size, void* d_ws, size_t ws_size,
                              hipStream_t stream) {
  const float* img = (const float*)d_in[0];
  const int* adj = (const int*)d_in[1];
  const float* ln_g = (const float*)d_in[2];
  const float* ln_b = (const float*)d_in[3];
  const float* gcn_wq = (const float*)d_in[4];
  const float* gcn_wk = (const float*)d_in[5];
  const float* gcn_wv = (const float*)d_in[6];
  const float* wq = (const float*)d_in[7];
  const float* wk = (const float*)d_in[8];
  const float* wv = (const float*)d_in[9];
  const float* w_kf = (const float*)d_in[10];
  const float* w_kf2 = (const float*)d_in[11];
  const float* w_kf3 = (const float*)d_in[12];
  const float* sD = (const float*)d_in[13];
  const float* sD2 = (const float*)d_in[14];
  const float* randmat = (const float*)d_in[15];
  const float* conv1_w = (const float*)d_in[16];
  const float* conv1_b = (const float*)d_in[17];
  const float* bn_g = (const float*)d_in[18];
  const float* bn_b = (const float*)d_in[19];
  const float* conv2_w = (const float*)d_in[20];
  const float* conv2_b = (const float*)d_in[21];
  const float* emb_w = (const float*)d_in[22];
  const float* emb_b = (const float*)d_in[23];
  const float* upool_w = (const float*)d_in[24];
  const float* upool_b = (const float*)d_in[25];
  const float* upoolout_w = (const float*)d_in[26];
  const float* upoolout_b = (const float*)d_in[27];
  float* out = (float*)d_out;

  uint32_t k2a, k2b, k99a, k99b;
  threefry2x32(0u, 42u, 0u, 2u, &k2a, &k2b);
  threefry2x32(0u, 42u, 0u, 99u, &k99a, &k99b);

  const float SCALE = (float)(1.0 / sqrt(384.0));

  k_patch<<<2048, 256, 0, stream>>>(img, conv1_w, conv1_b, bn_g, bn_b, conv2_w, conv2_b);
  k_gemm<8><<<256, 384, 8 * 384 * sizeof(float), stream>>>(
      emb_w, emb_b, SEL_PATCH, SEL_X, -1, 2048, 1536, 384, 0);

  auto attention = [&](int i, int t, int label) {
    int rows = NB * t;
    int bht = NB * NHD * t;
    int bht4 = bht / 4;
    int use_adj2 = (t == 64) ? 1 : 0;
    k_lngcn<<<rows, 384, 0, stream>>>(ln_g + i * 384, ln_b + i * 384,
                                      gcn_wq + i * 2304, gcn_wk + i * 2304,
                                      gcn_wv + i * 2304, t);
    k_adjmm<<<bht4, 64, 0, stream>>>(adj, use_adj2, t);
    if (rows == 2048) {
      k_gemm<4><<<512, 384, 4 * 384 * sizeof(float), stream>>>(
          wq + i * 147456, nullptr, SEL_Q4, SEL_Q, -1, rows, 384, 384, 0);
      k_gemm<4><<<512, 384, 4 * 384 * sizeof(float), stream>>>(
          wk + i * 147456, nullptr, SEL_K4, SEL_K, -1, rows, 384, 384, 0);
    } else {
      k_gemm<2><<<256, 384, 2 * 384 * sizeof(float), stream>>>(
          wq + i * 147456, nullptr, SEL_Q4, SEL_Q, -1, rows, 384, 384, 0);
      k_gemm<2><<<256, 384, 2 * 384 * sizeof(float), stream>>>(
          wk + i * 147456, nullptr, SEL_K4, SEL_K, -1, rows, 384, 384, 0);
    }
    k_kf<<<rows, 64, 0, stream>>>(w_kf + i * 6144);
    k_rm<<<NB, 64, 0, stream>>>(t);
    const float* Wp = label ? (w_kf3 + i * 512) : (w_kf2 + i * 2048);
    const float* sDp = label ? (sD2 + i * 512) : (sD + i * 2048);
    int totr = NB * NHD * t;
    k_rmd<<<(totr + 255) / 256, 256, 0, stream>>>(Wp, sDp, t);
    k_score<<<bht4, t, 0, stream>>>(SCALE, t);
    k_mixsoft<<<bht, t, t * sizeof(float), stream>>>(randmat + i * 64, adj, use_adj2, t);
    k_attnv<<<bht4, 64, 0, stream>>>(t);
    if (rows == 2048) {
      k_gemm<4><<<512, 384, 4 * 384 * sizeof(float), stream>>>(
          wv + i * 147456, nullptr, SEL_Q4, SEL_X, SEL_X, rows, 384, 384, 1);
    } else {
      k_gemm<2><<<256, 384, 2 * 384 * sizeof(float), stream>>>(
          wv + i * 147456, nullptr, SEL_Q4, SEL_X, SEL_X, rows, 384, 384, 1);
    }
  };

  attention(0, 256, 0);
  attention(1, 256, 0);

  // pooling at i==2
  k_gemm<2><<<1024, 64, 2 * 384 * sizeof(float), stream>>>(
      upool_w, upool_b, SEL_X, SEL_LOGITS, -1, 2048, 384, 64, 0);
  k_gumbel_pool<<<512, 256, 0, stream>>>(k2a, k2b);
  k_poolx<<<512, 384, 0, stream>>>();
  k_copyx<<<(NB * 64 * NDIM + 255) / 256, 256, 0, stream>>>(NB * 64 * NDIM);
  k_pooladj1<<<512, 256, 0, stream>>>(adj);
  k_pooladj2<<<512, 64, 0, stream>>>();

  attention(2, 64, 1);
  attention(3, 64, 1);

  k_outlogits<<<512, 64, 0, stream>>>(upoolout_w, upoolout_b);
  k_final<<<8, 384, 0, stream>>>(k99a, k99b, out);
}